// Round 4
// baseline (209.406 us; speedup 1.0000x reference)
//
#include <hip/hip_runtime.h>
#include <cmath>

#define PHI_F   1.6180339887498949f
#define INV2PI  0.15915494309189535f
#define SQRT2F  1.41421356237309505f
#define TLASTF  (63.0f * 1.6180339887498949f)
#define LOG2EF  1.4426950408889634f

typedef __attribute__((ext_vector_type(8))) short bf16x8;
typedef __attribute__((ext_vector_type(4))) float f32x4;

// fp32 -> (hi, lo) bf16 (RN-even via bit trick)
__device__ __forceinline__ void split1(float x, unsigned short& hi, unsigned short& lo) {
    const unsigned u = __float_as_uint(x);
    const unsigned r = (u + 0x7fffu + ((u >> 16) & 1u)) & 0xffff0000u;
    hi = (unsigned short)(r >> 16);
    const float l = x - __uint_as_float(r);
    const unsigned ul = __float_as_uint(l);
    lo = (unsigned short)((ul + 0x7fffu + ((ul >> 16) & 1u)) >> 16);
}

// grid barrier: monotonic per-call counter (memset to 0 each kernel_launch).
// agent-scope RMW release-sequence + acquire spin; ~1-2us.
__device__ __forceinline__ void gridbar(unsigned* cnt) {
    __syncthreads();
    if (threadIdx.x == 0) {
        __threadfence();
        __hip_atomic_fetch_add(cnt, 1u, __ATOMIC_ACQ_REL, __HIP_MEMORY_SCOPE_AGENT);
        while (__hip_atomic_load(cnt, __ATOMIC_ACQUIRE, __HIP_MEMORY_SCOPE_AGENT) < 256u)
            __builtin_amdgcn_s_sleep(2);
        __threadfence();
    }
    __syncthreads();
}

// One 16x16 NT fragment over k-chunk [k0,k0+KC): pure loads + 3 MFMA/32-step.
// C/D: col = lane&15, row = 4*(lane>>4) + reg
template<int KC>
__device__ __forceinline__ f32x4 frag3(
    const unsigned short* __restrict__ Ah, const unsigned short* __restrict__ Al,
    const unsigned short* __restrict__ Bh, const unsigned short* __restrict__ Bl,
    int lda, int ldb, int m0, int n0, int k0, int lane)
{
    const int rr = lane & 15;
    const int ko = (lane >> 4) * 8;
    const unsigned short* aph = Ah + (size_t)(m0 + rr) * lda + k0 + ko;
    const unsigned short* apl = Al + (size_t)(m0 + rr) * lda + k0 + ko;
    const unsigned short* bph = Bh + (size_t)(n0 + rr) * ldb + k0 + ko;
    const unsigned short* bpl = Bl + (size_t)(n0 + rr) * ldb + k0 + ko;
    f32x4 acc  = {0.f, 0.f, 0.f, 0.f};
    f32x4 acc2 = {0.f, 0.f, 0.f, 0.f};
    #pragma unroll 4
    for (int kk = 0; kk < KC; kk += 32) {
        const bf16x8 ah = *(const bf16x8*)(aph + kk);
        const bf16x8 al = *(const bf16x8*)(apl + kk);
        const bf16x8 bh = *(const bf16x8*)(bph + kk);
        const bf16x8 bl = *(const bf16x8*)(bpl + kk);
        acc  = __builtin_amdgcn_mfma_f32_16x16x32_bf16(ah, bh, acc,  0, 0, 0);
        acc2 = __builtin_amdgcn_mfma_f32_16x16x32_bf16(ah, bl, acc2, 0, 0, 0);
        acc2 = __builtin_amdgcn_mfma_f32_16x16x32_bf16(al, bh, acc2, 0, 0, 0);
    }
    return acc + acc2;
}

// ---------------------------------------------------------------------------
// Persistent mega-kernel: 256 blocks x 512 threads (1 block/CU, co-resident).
// P0 weight-split + recurrence | th0 | pv0 | th1 | pv1 | logits; 5 grid bars.
// ---------------------------------------------------------------------------
__global__ __launch_bounds__(512) void mega(
    const int* __restrict__ ids, const float* __restrict__ te,
    const float* __restrict__ W, const float* __restrict__ bias,
    const float* __restrict__ Pr, const float* __restrict__ Pi,
    const float* __restrict__ op, float* __restrict__ out,
    unsigned* __restrict__ cnt,
    unsigned short* __restrict__ whi, unsigned short* __restrict__ wlo,
    float* __restrict__ h, unsigned short* __restrict__ hh,
    unsigned short* __restrict__ hl,
    unsigned short* __restrict__ cth, unsigned short* __restrict__ ctl,
    unsigned short* __restrict__ sth, unsigned short* __restrict__ stl)
{
    __shared__ float red[8][260];
    __shared__ int sid[64];
    const int tid = threadIdx.x, bid = blockIdx.x;
    const int lane = tid & 63, w = tid >> 6;

    // ---------------- P0a: split all weights to hi/lo bf16 ----------------
    {
        const int g = bid * 512 + tid;  // 0..131071; 7 float4 each
        const float* const srcs[7] = {W, W + 524288, Pr, Pr + 524288,
                                      Pi, Pi + 524288, op};
        #pragma unroll
        for (int k = 0; k < 7; ++k) {
            const float4 v = *(const float4*)(srcs[k] + (size_t)g * 4);
            ushort4 h4, l4;
            split1(v.x, h4.x, l4.x); split1(v.y, h4.y, l4.y);
            split1(v.z, h4.z, l4.z); split1(v.w, h4.w, l4.w);
            const size_t j = ((size_t)k * 131072 + g) * 4;
            *(ushort4*)(whi + j) = h4;
            *(ushort4*)(wlo + j) = l4;
        }
    }
    // ---------------- P0b: rotation recurrence (blocks 0..127) ------------
    if (bid < 128) {
        if (tid < 64) sid[tid] = ids[bid * 64 + tid];
        __syncthreads();
        const int d = tid;  // 0..511
        float wv[2][8], bev[2][8];
        #pragma unroll
        for (int j = 0; j < 8; ++j) {
            const int id = sid[j];
            wv[0][j]  = te[id * 1024 + d];
            bev[0][j] = te[id * 1024 + 512 + d];
        }
        float v = 0.f;
        #pragma unroll
        for (int g = 0; g < 8; ++g) {
            const int cur = g & 1, nxt = cur ^ 1;
            if (g < 7) {
                #pragma unroll
                for (int j = 0; j < 8; ++j) {
                    const int id = sid[(g + 1) * 8 + j];
                    wv[nxt][j]  = te[id * 1024 + d];
                    bev[nxt][j] = te[id * 1024 + 512 + d];
                }
            }
            #pragma unroll
            for (int j = 0; j < 8; ++j) {
                const int t = g * 8 + j;
                const float rlam = __builtin_amdgcn_rcpf(1.0f + fabsf(wv[cur][j]));
                const float a2 = (SQRT2F * INV2PI) * rlam;
                const float b2 = fmaf(2.0f * INV2PI, bev[cur][j],
                                      fmaf((float)t, 2.0f * PHI_F * INV2PI, 0.125f));
                v = __builtin_amdgcn_sinf(__builtin_amdgcn_fractf(fmaf(v, a2, b2)));
            }
        }
        const float u = SQRT2F * v;
        h[bid * 512 + d] = u;
        unsigned short uh, ul;
        split1(u, uh, ul);
        hh[bid * 512 + d] = uh;
        hl[bid * 512 + d] = ul;
    }
    gridbar(cnt + 0);

    // ---------------- layers ----------------
    #pragma unroll 1
    for (int l = 0; l < 2; ++l) {
        // ---- theta: M=128,N=1024,K=512; 2 tiles/block, 4-way split-K ----
        {
            const unsigned short* Wh = whi + (size_t)l * 524288;
            const unsigned short* Wl = wlo + (size_t)l * 524288;
            const int tile = bid * 2 + (w >> 2);
            const int mt = tile >> 6, nt = tile & 63;
            const f32x4 acc = frag3<128>(hh, hl, Wh, Wl, 512, 512,
                                         mt * 16, nt * 16, (w & 3) * 128, lane);
            *(f32x4*)&red[w][lane * 4] = acc;
            __syncthreads();
            if ((w & 3) < 2) {
                const int grp = (w >> 2) * 4;
                float4 s = {0.f, 0.f, 0.f, 0.f};
                #pragma unroll
                for (int ww = 0; ww < 4; ++ww) {
                    const float4 q = *(const float4*)&red[grp + ww][lane * 4];
                    s.x += q.x; s.y += q.y; s.z += q.z; s.w += q.w;
                }
                const int sel = w & 3;  // 0 -> cos, 1 -> sin
                unsigned short* dh = sel ? sth : cth;
                unsigned short* dl = sel ? stl : ctl;
                const int col = lane & 15, rb = (lane >> 4) * 4;
                const int n = nt * 16 + col;
                const float bn = bias[l * 1024 + n] + TLASTF;
                const float sv[4] = {s.x, s.y, s.z, s.w};
                #pragma unroll
                for (int r = 0; r < 4; ++r) {
                    const int m = mt * 16 + rb + r;
                    const float fr = __builtin_amdgcn_fractf((sv[r] + bn) * INV2PI);
                    const float vv = sel ? __builtin_amdgcn_sinf(fr)
                                         : __builtin_amdgcn_cosf(fr);
                    unsigned short vh, vl;
                    split1(vv, vh, vl);
                    dh[m * 1024 + n] = vh;
                    dl[m * 1024 + n] = vl;
                }
            }
        }
        gridbar(cnt + 1 + 2 * l);

        // ---- pv: h += silu(ct@Pr^T + st@Pi^T); M=128,N=512,K=1024x2 ----
        {
            const int mt = bid >> 5, nt = bid & 31;
            const int p = w >> 2, k0 = (w & 3) * 256;
            const unsigned short* Ah = p ? sth : cth;
            const unsigned short* Al = p ? stl : ctl;
            const size_t boff = (p ? 2097152u : 1048576u) + (size_t)l * 524288;
            const unsigned short* Bh = whi + boff;
            const unsigned short* Bl = wlo + boff;
            const f32x4 acc = frag3<256>(Ah, Al, Bh, Bl, 1024, 1024,
                                         mt * 16, nt * 16, k0, lane);
            *(f32x4*)&red[w][lane * 4] = acc;
            __syncthreads();
            if (w == 0) {
                float4 s = {0.f, 0.f, 0.f, 0.f};
                #pragma unroll
                for (int ww = 0; ww < 8; ++ww) {
                    const float4 q = *(const float4*)&red[ww][lane * 4];
                    s.x += q.x; s.y += q.y; s.z += q.z; s.w += q.w;
                }
                const int col = lane & 15, rb = (lane >> 4) * 4;
                const int dn = nt * 16 + col;
                const float sv[4] = {s.x, s.y, s.z, s.w};
                #pragma unroll
                for (int r = 0; r < 4; ++r) {
                    const int m = mt * 16 + rb + r;
                    const float x = sv[r];
                    const float sig = __builtin_amdgcn_rcpf(
                        1.0f + __builtin_amdgcn_exp2f(-LOG2EF * x));
                    const float val = h[m * 512 + dn] + x * sig;
                    h[m * 512 + dn] = val;
                    unsigned short vh, vl;
                    split1(val, vh, vl);
                    hh[m * 512 + dn] = vh;
                    hl[m * 512 + dn] = vl;
                }
            }
        }
        gridbar(cnt + 2 + 2 * l);
    }

    // ---------------- logits: M=128,N=1024,K=512; 2 tiles/block ----------
    {
        const unsigned short* oph = whi + 3145728;
        const unsigned short* opl = wlo + 3145728;
        const int tile = bid * 2 + (w >> 2);
        const int mt = tile >> 6, nt = tile & 63;
        const f32x4 acc = frag3<128>(hh, hl, oph, opl, 512, 512,
                                     mt * 16, nt * 16, (w & 3) * 128, lane);
        *(f32x4*)&red[w][lane * 4] = acc;
        __syncthreads();
        if ((w & 3) == 0) {
            const int grp = (w >> 2) * 4;
            float4 s = {0.f, 0.f, 0.f, 0.f};
            #pragma unroll
            for (int ww = 0; ww < 4; ++ww) {
                const float4 q = *(const float4*)&red[grp + ww][lane * 4];
                s.x += q.x; s.y += q.y; s.z += q.z; s.w += q.w;
            }
            const int col = lane & 15, rb = (lane >> 4) * 4;
            const int n = nt * 16 + col;
            const float sv[4] = {s.x, s.y, s.z, s.w};
            #pragma unroll
            for (int r = 0; r < 4; ++r)
                out[(size_t)(mt * 16 + rb + r) * 1024 + n] = sv[r];
        }
    }
}

// ---------------------------------------------------------------------------
// B=128, S=64, V=1024, D=512, N=1024, L=2
// ws: cnt 64B | whi/wlo 3,670,016 ushort each | h 65,536 f32 | hh/hl |
//     cth/ctl/sth/stl 131,072 ushort each   (~16.3 MiB)
// ---------------------------------------------------------------------------
extern "C" void kernel_launch(void* const* d_in, const int* in_sizes, int n_in,
                              void* d_out, int out_size, void* d_ws, size_t ws_size,
                              hipStream_t stream) {
    const int*   ids   = (const int*)d_in[0];
    const float* te    = (const float*)d_in[1];
    const float* W     = (const float*)d_in[2];
    const float* bias  = (const float*)d_in[3];
    const float* Pr    = (const float*)d_in[4];
    const float* Pi    = (const float*)d_in[5];
    const float* oproj = (const float*)d_in[6];
    float* out = (float*)d_out;

    unsigned*       cnt = (unsigned*)d_ws;
    unsigned short* whi = (unsigned short*)((char*)d_ws + 256);
    unsigned short* wlo = whi + 3670016;
    float*          h   = (float*)(wlo + 3670016);
    unsigned short* hh  = (unsigned short*)(h + 65536);
    unsigned short* hl  = hh + 65536;
    unsigned short* cth = hl + 65536;
    unsigned short* ctl = cth + 131072;
    unsigned short* sth = ctl + 131072;
    unsigned short* stl = sth + 131072;

    hipMemsetAsync(d_ws, 0, 64, stream);  // zero barrier counters
    mega<<<256, 512, 0, stream>>>(ids, te, W, bias, Pr, Pi, oproj, out,
                                  cnt, whi, wlo, h, hh, hl, cth, ctl, sth, stl);
}

// Round 5
// 51.226 us; speedup vs baseline: 4.0879x; 4.0879x over previous
//
#include <hip/hip_runtime.h>
#include <hip/hip_bf16.h>
#include <cmath>

#define PHI_F   1.6180339887498949f
#define INV2PI  0.15915494309189535f
#define SQRT2F  1.41421356237309505f
#define TLASTF  (63.0f * 1.6180339887498949f)
#define LOG2EF  1.4426950408889634f

typedef __attribute__((ext_vector_type(8))) short bf16x8;
typedef __attribute__((ext_vector_type(4))) float f32x4;

// fp32 -> (hi, lo) bf16 (RN-even via bit trick) — used on activations only
__device__ __forceinline__ void split1(float x, unsigned short& hi, unsigned short& lo) {
    const unsigned u = __float_as_uint(x);
    const unsigned r = (u + 0x7fffu + ((u >> 16) & 1u)) & 0xffff0000u;
    hi = (unsigned short)(r >> 16);
    const float l = x - __uint_as_float(r);
    const unsigned ul = __float_as_uint(l);
    lo = (unsigned short)((ul + 0x7fffu + ((ul >> 16) & 1u)) >> 16);
}

// 8x fp32 -> bf16x8 (RN-even), inline weight conversion
__device__ __forceinline__ bf16x8 cvt8(float4 a, float4 b) {
    union { bf16x8 v; __hip_bfloat162 h2[4]; } u;
    u.h2[0] = __float22bfloat162_rn(make_float2(a.x, a.y));
    u.h2[1] = __float22bfloat162_rn(make_float2(a.z, a.w));
    u.h2[2] = __float22bfloat162_rn(make_float2(b.x, b.y));
    u.h2[3] = __float22bfloat162_rn(make_float2(b.z, b.w));
    return u.v;
}

// ---------------------------------------------------------------------------
// Recurrence: 256 blocks x 256 thr (b = bid>>1, d = (bid&1)*256+tid).
// Depth-8 register prefetch hides te-gather latency under the serial sin chain.
// ---------------------------------------------------------------------------
__global__ __launch_bounds__(256) void rinrec_k(
    const int* __restrict__ ids, const float* __restrict__ te,
    float* __restrict__ h, unsigned short* __restrict__ hh,
    unsigned short* __restrict__ hl)
{
    const int b = blockIdx.x >> 1;
    const int d = ((blockIdx.x & 1) << 8) + threadIdx.x;
    __shared__ int sid[64];
    if (threadIdx.x < 64) sid[threadIdx.x] = ids[b * 64 + threadIdx.x];
    __syncthreads();

    float wv[2][8], bev[2][8];
    #pragma unroll
    for (int j = 0; j < 8; ++j) {
        const int id = sid[j];
        wv[0][j]  = te[id * 1024 + d];
        bev[0][j] = te[id * 1024 + 512 + d];
    }
    float v = 0.f;
    #pragma unroll
    for (int g = 0; g < 8; ++g) {
        const int cur = g & 1, nxt = cur ^ 1;
        if (g < 7) {
            #pragma unroll
            for (int j = 0; j < 8; ++j) {
                const int id = sid[(g + 1) * 8 + j];
                wv[nxt][j]  = te[id * 1024 + d];
                bev[nxt][j] = te[id * 1024 + 512 + d];
            }
        }
        #pragma unroll
        for (int j = 0; j < 8; ++j) {
            const int t = g * 8 + j;
            const float rlam = __builtin_amdgcn_rcpf(1.0f + fabsf(wv[cur][j]));
            const float a2 = (SQRT2F * INV2PI) * rlam;
            const float b2 = fmaf(2.0f * INV2PI, bev[cur][j],
                                  fmaf((float)t, 2.0f * PHI_F * INV2PI, 0.125f));
            v = __builtin_amdgcn_sinf(__builtin_amdgcn_fractf(fmaf(v, a2, b2)));
        }
    }
    const float u = SQRT2F * v;
    h[b * 512 + d] = u;
    unsigned short uh, ul;
    split1(u, uh, ul);
    hh[b * 512 + d] = uh;
    hl[b * 512 + d] = ul;
}

// ---------------------------------------------------------------------------
// 16x16 NT fragment, A = bf16 hi/lo pair, B = fp32 converted inline.
// 4 x 16B loads + 2 MFMA per 32-wide k-step.
// C/D: col = lane&15, row = 4*(lane>>4) + reg
// ---------------------------------------------------------------------------
template<int KC>
__device__ __forceinline__ f32x4 frag2(
    const unsigned short* __restrict__ Ah, const unsigned short* __restrict__ Al,
    const float* __restrict__ B,
    int lda, int ldb, int m0, int n0, int k0, int lane)
{
    const int rr = lane & 15;
    const int ko = (lane >> 4) * 8;
    const unsigned short* aph = Ah + (size_t)(m0 + rr) * lda + k0 + ko;
    const unsigned short* apl = Al + (size_t)(m0 + rr) * lda + k0 + ko;
    const float*          bp  = B  + (size_t)(n0 + rr) * ldb + k0 + ko;
    f32x4 acc  = {0.f, 0.f, 0.f, 0.f};
    f32x4 acc2 = {0.f, 0.f, 0.f, 0.f};
    #pragma unroll 4
    for (int kk = 0; kk < KC; kk += 32) {
        const bf16x8 ah = *(const bf16x8*)(aph + kk);
        const bf16x8 al = *(const bf16x8*)(apl + kk);
        const float4 b0 = *(const float4*)(bp + kk);
        const float4 b1 = *(const float4*)(bp + kk + 4);
        const bf16x8 bh = cvt8(b0, b1);
        acc  = __builtin_amdgcn_mfma_f32_16x16x32_bf16(ah, bh, acc,  0, 0, 0);
        acc2 = __builtin_amdgcn_mfma_f32_16x16x32_bf16(al, bh, acc2, 0, 0, 0);
    }
    return acc + acc2;
}

// ---------------------------------------------------------------------------
// theta: ct/st = cos/sin(h @ W^T + bias + t_last), written as hi/lo bf16.
// M=128,N=1024,K=512. 512 blocks (1 tile) x 4 waves (split-K 128).
// ---------------------------------------------------------------------------
__global__ __launch_bounds__(256) void theta_k(
    const unsigned short* __restrict__ hh, const unsigned short* __restrict__ hl,
    const float* __restrict__ W, const float* __restrict__ bias,
    unsigned short* __restrict__ cth, unsigned short* __restrict__ ctl,
    unsigned short* __restrict__ sth, unsigned short* __restrict__ stl)
{
    __shared__ float red[4][260];
    const int lane = threadIdx.x & 63;
    const int w = threadIdx.x >> 6;
    const int nt = blockIdx.x & 63, mt = blockIdx.x >> 6;
    const f32x4 acc = frag2<128>(hh, hl, W, 512, 512,
                                 mt * 16, nt * 16, w * 128, lane);
    *(f32x4*)&red[w][lane * 4] = acc;
    __syncthreads();
    if (w < 2) {
        float4 s = {0.f, 0.f, 0.f, 0.f};
        #pragma unroll
        for (int ww = 0; ww < 4; ++ww) {
            const float4 q = *(const float4*)&red[ww][lane * 4];
            s.x += q.x; s.y += q.y; s.z += q.z; s.w += q.w;
        }
        unsigned short* dh = w ? sth : cth;
        unsigned short* dl = w ? stl : ctl;
        const int col = lane & 15, rb = (lane >> 4) * 4;
        const int n = nt * 16 + col;
        const float bn = bias[n] + TLASTF;
        const float sv[4] = {s.x, s.y, s.z, s.w};
        #pragma unroll
        for (int r = 0; r < 4; ++r) {
            const int m = mt * 16 + rb + r;
            const float fr = __builtin_amdgcn_fractf((sv[r] + bn) * INV2PI);
            const float vv = w ? __builtin_amdgcn_sinf(fr)
                               : __builtin_amdgcn_cosf(fr);
            unsigned short vh, vl;
            split1(vv, vh, vl);
            dh[m * 1024 + n] = vh;
            dl[m * 1024 + n] = vl;
        }
    }
}

// ---------------------------------------------------------------------------
// pv: h += silu(ct @ Pr^T + st @ Pi^T); h rewritten fp32 + hi/lo bf16.
// M=128,N=512,K=1024 per pair. 256 blocks x 8 waves (pair = w>>2, kchunk 256).
// ---------------------------------------------------------------------------
__global__ __launch_bounds__(512) void pv_k(
    const unsigned short* __restrict__ cth, const unsigned short* __restrict__ ctl,
    const unsigned short* __restrict__ sth, const unsigned short* __restrict__ stl,
    const float* __restrict__ Pr, const float* __restrict__ Pi,
    float* __restrict__ h, unsigned short* __restrict__ hh,
    unsigned short* __restrict__ hl)
{
    __shared__ float red[8][260];
    const int lane = threadIdx.x & 63;
    const int w = threadIdx.x >> 6;
    const int nt = blockIdx.x & 31, mt = blockIdx.x >> 5;
    const int p = w >> 2, k0 = (w & 3) * 256;
    const unsigned short* Ah = p ? sth : cth;
    const unsigned short* Al = p ? stl : ctl;
    const float* B = p ? Pi : Pr;
    const f32x4 acc = frag2<256>(Ah, Al, B, 1024, 1024,
                                 mt * 16, nt * 16, k0, lane);
    *(f32x4*)&red[w][lane * 4] = acc;
    __syncthreads();
    if (w == 0) {
        float4 s = {0.f, 0.f, 0.f, 0.f};
        #pragma unroll
        for (int ww = 0; ww < 8; ++ww) {
            const float4 q = *(const float4*)&red[ww][lane * 4];
            s.x += q.x; s.y += q.y; s.z += q.z; s.w += q.w;
        }
        const int col = lane & 15, rb = (lane >> 4) * 4;
        const int dn = nt * 16 + col;
        const float sv[4] = {s.x, s.y, s.z, s.w};
        #pragma unroll
        for (int r = 0; r < 4; ++r) {
            const int m = mt * 16 + rb + r;
            const float x = sv[r];
            const float sig = __builtin_amdgcn_rcpf(
                1.0f + __builtin_amdgcn_exp2f(-LOG2EF * x));
            const float val = h[m * 512 + dn] + x * sig;
            h[m * 512 + dn] = val;
            unsigned short vh, vl;
            split1(val, vh, vl);
            hh[m * 512 + dn] = vh;
            hl[m * 512 + dn] = vl;
        }
    }
}

// ---------------------------------------------------------------------------
// logits = h @ oproj^T  (M=128,N=1024,K=512). 512 blocks x 4 waves.
// ---------------------------------------------------------------------------
__global__ __launch_bounds__(256) void logits_k(
    const unsigned short* __restrict__ hh, const unsigned short* __restrict__ hl,
    const float* __restrict__ op, float* __restrict__ out)
{
    __shared__ float red[4][260];
    const int lane = threadIdx.x & 63;
    const int w = threadIdx.x >> 6;
    const int nt = blockIdx.x & 63, mt = blockIdx.x >> 6;
    const f32x4 acc = frag2<128>(hh, hl, op, 512, 512,
                                 mt * 16, nt * 16, w * 128, lane);
    *(f32x4*)&red[w][lane * 4] = acc;
    __syncthreads();
    if (w == 0) {
        float4 s = {0.f, 0.f, 0.f, 0.f};
        #pragma unroll
        for (int ww = 0; ww < 4; ++ww) {
            const float4 q = *(const float4*)&red[ww][lane * 4];
            s.x += q.x; s.y += q.y; s.z += q.z; s.w += q.w;
        }
        const int col = lane & 15, rb = (lane >> 4) * 4;
        const int n = nt * 16 + col;
        const float sv[4] = {s.x, s.y, s.z, s.w};
        #pragma unroll
        for (int r = 0; r < 4; ++r)
            out[(size_t)(mt * 16 + rb + r) * 1024 + n] = sv[r];
    }
}

// ---------------------------------------------------------------------------
// B=128, S=64, V=1024, D=512, N=1024, L=2
// ws: h 65,536 f32 | hh/hl 65,536 us | cth/ctl/sth/stl 131,072 us (~1.5 MiB)
// ---------------------------------------------------------------------------
extern "C" void kernel_launch(void* const* d_in, const int* in_sizes, int n_in,
                              void* d_out, int out_size, void* d_ws, size_t ws_size,
                              hipStream_t stream) {
    const int*   ids   = (const int*)d_in[0];
    const float* te    = (const float*)d_in[1];
    const float* W     = (const float*)d_in[2];
    const float* bias  = (const float*)d_in[3];
    const float* Pr    = (const float*)d_in[4];
    const float* Pi    = (const float*)d_in[5];
    const float* oproj = (const float*)d_in[6];
    float* out = (float*)d_out;

    float*          h   = (float*)d_ws;
    unsigned short* hh  = (unsigned short*)(h + 65536);
    unsigned short* hl  = hh + 65536;
    unsigned short* cth = hl + 65536;
    unsigned short* ctl = cth + 131072;
    unsigned short* sth = ctl + 131072;
    unsigned short* stl = sth + 131072;

    rinrec_k<<<256, 256, 0, stream>>>(ids, te, h, hh, hl);

    for (int l = 0; l < 2; ++l) {
        theta_k<<<512, 256, 0, stream>>>(
            hh, hl, W + (size_t)l * 524288, bias + l * 1024,
            cth, ctl, sth, stl);
        pv_k<<<256, 512, 0, stream>>>(
            cth, ctl, sth, stl,
            Pr + (size_t)l * 524288, Pi + (size_t)l * 524288,
            h, hh, hl);
    }

    logits_k<<<512, 256, 0, stream>>>(hh, hl, oproj, out);
}